// Round 11
// baseline (383.765 us; speedup 1.0000x reference)
//
#include <hip/hip_runtime.h>
#include <hip/hip_bf16.h>

#define N_NODES 100000
#define N_EDGES 1600000
#define IN_CH 50
#define NPB 512                                   // nodes per bucket (dst >> 9)
#define NB ((N_NODES + NPB - 1) / NPB)            // 196 buckets
#define CAPLOG 14                                 // 16384 slots per bucket (max ~8.6K)
#define EPB 4096
#define NBLK_A ((N_EDGES + EPB - 1) / EPB)        // 391 blocks
#define PAD_BLOCKS ((N_NODES * 64) / 256)         // 25000

// ---- 1. init: block 0 = cursors + W transposes; blocks 1.. = pad x->xb bf16 ----
__global__ __launch_bounds__(256) void init_pad_kernel(
    const float* __restrict__ x, const float* __restrict__ W1,
    const float* __restrict__ W2, unsigned short* __restrict__ xb,
    int* __restrict__ bucket_cursor, float* __restrict__ Wt1,
    float* __restrict__ Wt2) {
    if (blockIdx.x == 0) {
        int t = threadIdx.x;
        if (t < NB) bucket_cursor[t] = t << CAPLOG;
        // Wt1[j][k]: k<50 -> W1[k][j]; 64<=k<114 -> W1[k-14][j]; else 0
        for (int idx = t; idx < 64 * 128; idx += 256) {
            int j = idx >> 7, k = idx & 127;
            float v = 0.0f;
            if (k < IN_CH) v = W1[k * 64 + j];
            else if (k >= 64 && k < 64 + IN_CH) v = W1[(k - 14) * 64 + j];
            Wt1[idx] = v;
        }
        // Wt2[j][k] = W2[k][j], k in [0,128)
        for (int idx = t; idx < 32 * 128; idx += 256) {
            int j = idx >> 7, k = idx & 127;
            Wt2[idx] = W2[k * 32 + j];
        }
    } else {
        int t = (blockIdx.x - 1) * 256 + threadIdx.x;        // < N_NODES*64
        int n = t >> 6, c = t & 63;
        float v = (c < IN_CH) ? x[n * IN_CH + c] : 0.0f;
        __hip_bfloat16 hb = __float2bfloat16(v);
        xb[t] = *(unsigned short*)&hb;
    }
}

// ---- 2. bin edges as packed u32 into fixed-capacity buckets ----
__global__ __launch_bounds__(256) void bucket_bin(const int* __restrict__ src,
                                                  const int* __restrict__ dst,
                                                  int* __restrict__ bucket_cursor,
                                                  unsigned* __restrict__ binned) {
    __shared__ int bc[NB];
    __shared__ int boff[NB];
    int t = threadIdx.x;
    if (t < NB) bc[t] = 0;
    __syncthreads();
    int e0 = blockIdx.x * EPB;
    int e1 = min(e0 + EPB, N_EDGES);
    for (int i = e0 + t; i < e1; i += 256)
        atomicAdd(&bc[dst[i] >> 9], 1);
    __syncthreads();
    if (t < NB) {
        int v = bc[t];
        boff[t] = v ? atomicAdd(&bucket_cursor[t], v) : 0;
        bc[t] = 0;                                 // reuse as local cursor
    }
    __syncthreads();
    for (int i = e0 + t; i < e1; i += 256) {
        int d = dst[i];
        int b = d >> 9;
        int k = atomicAdd(&bc[b], 1);
        binned[boff[b] + k] = ((unsigned)(d & 511) << 17) | (unsigned)src[i];
    }
}

// ---- 3. per-bucket fine sort (u32 payload) -> cnt, row_start, csr_src ----
__global__ __launch_bounds__(256) void bucket_fine(
    const unsigned* __restrict__ binned, const int* __restrict__ bucket_cursor,
    int* __restrict__ cnt, int* __restrict__ row_start, int* __restrict__ csr_src) {
    __shared__ int lcnt[NPB];
    __shared__ int lofs[NPB];
    __shared__ int sc[256];
    int t = threadIdx.x;
    int b = blockIdx.x;
    int nbase = b * NPB;
    int bbase = b << CAPLOG;
    int ecnt  = bucket_cursor[b] - bbase;
    int ebase = b == 0 ? 0 : 0;                    // csr output is compacted separately
    // compact csr base: sum of previous bucket counts is unknown without scan;
    // instead keep csr_src in the same fixed-capacity layout: row_start absolute
    // into the binned-capacity space.
    lcnt[t] = 0; lcnt[t + 256] = 0;
    __syncthreads();
    for (int i = t; i < ecnt; i += 256)
        atomicAdd(&lcnt[(binned[bbase + i] >> 17) & 511], 1);
    __syncthreads();
    int v0 = lcnt[2 * t], v1 = lcnt[2 * t + 1];
    int pair = v0 + v1;
    sc[t] = pair;
    __syncthreads();
    for (int off = 1; off < 256; off <<= 1) {
        int tmp = (t >= off) ? sc[t - off] : 0;
        __syncthreads();
        sc[t] += tmp;
        __syncthreads();
    }
    int excl = sc[t] - pair;
    lofs[2 * t] = excl;
    lofs[2 * t + 1] = excl + v0;
    __syncthreads();
    {
        int n0 = nbase + t;
        if (n0 < N_NODES) { cnt[n0] = lcnt[t]; row_start[n0] = bbase + lofs[t]; }
        int n1 = nbase + t + 256;
        if (n1 < N_NODES) { cnt[n1] = lcnt[t + 256]; row_start[n1] = bbase + lofs[t + 256]; }
    }
    __syncthreads();
    for (int i = t; i < ecnt; i += 256) {
        unsigned p = binned[bbase + i];
        int d = (int)((p >> 17) & 511);
        int k = atomicAdd(&lofs[d], 1);
        csr_src[bbase + k] = (int)(p & 0x1FFFFu);
    }
    (void)ebase;
}

// unpack 8 bf16 from uint4, predicated fma into acc[0..8)
__device__ __forceinline__ void upadd8(float* a, uint4 v, float p) {
    a[0] = fmaf(p, __uint_as_float(v.x << 16), a[0]);
    a[1] = fmaf(p, __uint_as_float(v.x & 0xffff0000u), a[1]);
    a[2] = fmaf(p, __uint_as_float(v.y << 16), a[2]);
    a[3] = fmaf(p, __uint_as_float(v.y & 0xffff0000u), a[3]);
    a[4] = fmaf(p, __uint_as_float(v.z << 16), a[4]);
    a[5] = fmaf(p, __uint_as_float(v.z & 0xffff0000u), a[5]);
    a[6] = fmaf(p, __uint_as_float(v.w << 16), a[6]);
    a[7] = fmaf(p, __uint_as_float(v.w & 0xffff0000u), a[7]);
}

// wave-local LDS fence
#define WAVE_LDS_FENCE() __asm__ volatile("s_waitcnt lgkmcnt(0)" ::: "memory")

// Gather-mean of 4 nodes per wave, chains interleaved (proven R7/R10 shape).
__device__ __forceinline__ void gather4(
    const unsigned short* __restrict__ featb, const int* __restrict__ csr_src,
    const int* __restrict__ row_start, const int* __restrict__ cnt,
    int nb, int lane, float acc[4][8]) {
    int g  = lane >> 3;
    int cw = (lane & 7) * 8;
    int start[4], deg[4], sv[4];
    int dmax = 0;
    #pragma unroll
    for (int i = 0; i < 4; ++i) {
        start[i] = row_start[nb + i];
        deg[i]   = cnt[nb + i];
        dmax = max(dmax, deg[i]);
        #pragma unroll
        for (int c = 0; c < 8; ++c) acc[i][c] = 0.f;
    }
    #pragma unroll
    for (int i = 0; i < 4; ++i)
        sv[i] = (lane < deg[i]) ? csr_src[start[i] + lane] : 0;

    #pragma unroll
    for (int cb = 0; cb < 64; cb += 16) {
        if (cb >= dmax) break;                 // wave-uniform
        #pragma unroll
        for (int i = 0; i < 4; ++i) {
            int rem = deg[i] - cb;
            if (rem > 0) {                     // wave-uniform
                int s0 = __shfl(sv[i], cb + g);
                int s1 = __shfl(sv[i], cb + 8 + g);
                float p0 = (g < rem) ? 1.f : 0.f;
                float p1 = (g + 8 < rem) ? 1.f : 0.f;
                uint4 v0 = *(const uint4*)(featb + s0 * 64 + cw);
                uint4 v1 = *(const uint4*)(featb + s1 * 64 + cw);
                upadd8(acc[i], v0, p0);
                upadd8(acc[i], v1, p1);
            }
        }
    }
    if (dmax > 64) {                           // rare tail
        for (int i = 0; i < 4; ++i) {
            for (int c0 = 64; c0 < deg[i]; c0 += 64) {
                int rem = deg[i] - c0; if (rem > 64) rem = 64;
                int sx = (lane < rem) ? csr_src[start[i] + c0 + lane] : 0;
                for (int cb = 0; cb < rem; cb += 16) {
                    int s0 = __shfl(sx, cb + g);
                    int s1 = __shfl(sx, cb + 8 + g);
                    float p0 = (cb + g < rem) ? 1.f : 0.f;
                    float p1 = (cb + 8 + g < rem) ? 1.f : 0.f;
                    uint4 v0 = *(const uint4*)(featb + s0 * 64 + cw);
                    uint4 v1 = *(const uint4*)(featb + s1 * 64 + cw);
                    upadd8(acc[i], v0, p0);
                    upadd8(acc[i], v1, p1);
                }
            }
        }
    }
    #pragma unroll
    for (int i = 0; i < 4; ++i) {
        float inv = 1.0f / fmaxf((float)deg[i], 1.0f);
        #pragma unroll
        for (int c = 0; c < 8; ++c) {
            float t = acc[i][c];
            t += __shfl_xor(t, 8);
            t += __shfl_xor(t, 16);
            t += __shfl_xor(t, 32);
            acc[i][c] = t * inv;
        }
    }
}

__device__ __forceinline__ float bf16u(unsigned short u) {
    return __uint_as_float(((unsigned)u) << 16);
}

// ---- 4. layer 1: 4 nodes/wave; gather(xb) + GEMM via Wt1 float4 rows -> h1b ----
__global__ __launch_bounds__(256) void layer1_fused(
    const unsigned short* __restrict__ xb,
    const int* __restrict__ csr_src, const int* __restrict__ row_start,
    const int* __restrict__ cnt, const float* __restrict__ Wt1,
    const float* __restrict__ b1, unsigned short* __restrict__ h1b) {
    int wv   = threadIdx.x >> 6;
    int lane = threadIdx.x & 63;
    int nb   = (blockIdx.x * 4 + wv) * 4;      // N_NODES % 16 == 0

    float acc[4][8];
    gather4(xb, csr_src, row_start, cnt, nb, lane, acc);

    // feat rows of 128: [0,64)=self (xb incl. zero pad), [64,128)=mean
    __shared__ __align__(16) float feat[4][4][128];
    #pragma unroll
    for (int i = 0; i < 4; ++i) {
        feat[wv][i][lane] = bf16u(xb[((nb + i) << 6) + lane]);
        if (lane < 8) {
            *(float4*)&feat[wv][i][64 + lane * 8] =
                make_float4(acc[i][0], acc[i][1], acc[i][2], acc[i][3]);
            *(float4*)&feat[wv][i][64 + lane * 8 + 4] =
                make_float4(acc[i][4], acc[i][5], acc[i][6], acc[i][7]);
        }
    }
    WAVE_LDS_FENCE();

    float ao[4];
    float bb = b1[lane];
    #pragma unroll
    for (int i = 0; i < 4; ++i) ao[i] = bb;
    const float4* wrow = (const float4*)(Wt1 + lane * 128);
    #pragma unroll 4
    for (int k4 = 0; k4 < 32; ++k4) {
        float4 w = wrow[k4];
        #pragma unroll
        for (int i = 0; i < 4; ++i) {
            float4 f = *(const float4*)&feat[wv][i][k4 * 4];
            ao[i] = fmaf(f.x, w.x, ao[i]);
            ao[i] = fmaf(f.y, w.y, ao[i]);
            ao[i] = fmaf(f.z, w.z, ao[i]);
            ao[i] = fmaf(f.w, w.w, ao[i]);
        }
    }
    #pragma unroll
    for (int i = 0; i < 4; ++i) {
        float r = fmaxf(ao[i], 0.f);
        __hip_bfloat16 hb = __float2bfloat16(r);
        h1b[((nb + i) << 6) + lane] = *(unsigned short*)&hb;
    }
}

// ---- 5. layers 2+3: 4 nodes/wave; gather(h1b) + GEMM via Wt2 + ReLU + dot(W3) ----
__global__ __launch_bounds__(256) void layer23_fused(
    const unsigned short* __restrict__ h1b,
    const int* __restrict__ csr_src, const int* __restrict__ row_start,
    const int* __restrict__ cnt, const float* __restrict__ Wt2,
    const float* __restrict__ b2, const float* __restrict__ W3,
    const float* __restrict__ b3, float* __restrict__ out) {
    int wv   = threadIdx.x >> 6;
    int lane = threadIdx.x & 63;
    int nb   = (blockIdx.x * 4 + wv) * 4;

    float acc[4][8];
    gather4(h1b, csr_src, row_start, cnt, nb, lane, acc);

    __shared__ __align__(16) float featL[4][4][128];   // [0,64)=self, [64,128)=mean
    #pragma unroll
    for (int i = 0; i < 4; ++i) {
        featL[wv][i][lane] = bf16u(h1b[((nb + i) << 6) + lane]);
        if (lane < 8) {
            *(float4*)&featL[wv][i][64 + lane * 8] =
                make_float4(acc[i][0], acc[i][1], acc[i][2], acc[i][3]);
            *(float4*)&featL[wv][i][64 + lane * 8 + 4] =
                make_float4(acc[i][4], acc[i][5], acc[i][6], acc[i][7]);
        }
    }
    WAVE_LDS_FENCE();

    int hh = lane >> 5;                        // half-wave id: nodes nb+hh, nb+2+hh
    int j  = lane & 31;
    float a0 = b2[j], a1 = a0;
    const float4* wrow = (const float4*)(Wt2 + j * 128);
    #pragma unroll 4
    for (int k4 = 0; k4 < 32; ++k4) {
        float4 w  = wrow[k4];
        float4 f0 = *(const float4*)&featL[wv][hh][k4 * 4];
        float4 f1 = *(const float4*)&featL[wv][2 + hh][k4 * 4];
        a0 = fmaf(f0.x, w.x, a0); a0 = fmaf(f0.y, w.y, a0);
        a0 = fmaf(f0.z, w.z, a0); a0 = fmaf(f0.w, w.w, a0);
        a1 = fmaf(f1.x, w.x, a1); a1 = fmaf(f1.y, w.y, a1);
        a1 = fmaf(f1.z, w.z, a1); a1 = fmaf(f1.w, w.w, a1);
    }
    float w3 = W3[j];
    float c3 = b3[0];
    float v0 = fmaxf(a0, 0.f) * w3;
    float v1 = fmaxf(a1, 0.f) * w3;
    #pragma unroll
    for (int off = 1; off <= 16; off <<= 1) {
        v0 += __shfl_xor(v0, off);
        v1 += __shfl_xor(v1, off);
    }
    if (j == 0) {
        out[nb + hh]     = v0 + c3;
        out[nb + 2 + hh] = v1 + c3;
    }
}

extern "C" void kernel_launch(void* const* d_in, const int* in_sizes, int n_in,
                              void* d_out, int out_size, void* d_ws, size_t ws_size,
                              hipStream_t stream) {
    const float* x   = (const float*)d_in[0];
    const int*   ei  = (const int*)d_in[1];
    const int*   src = ei;
    const int*   dst = ei + N_EDGES;
    const float* W1  = (const float*)d_in[2];
    const float* b1  = (const float*)d_in[3];
    const float* W2  = (const float*)d_in[4];
    const float* b2  = (const float*)d_in[5];
    const float* W3  = (const float*)d_in[6];
    const float* b3  = (const float*)d_in[7];
    float* out = (float*)d_out;

    // ws (~52 MB): cursor | cnt | row_start | binned u32[NB<<14] 12.85MB |
    //   csr_src[NB<<14] 12.85MB | xb bf16 12.8MB | h1b bf16 12.8MB | Wt1 32KB | Wt2 16KB
    char* ws = (char*)d_ws;
    auto align = [](size_t v) { return (v + 255) & ~(size_t)255; };
    size_t o = 0;
    int* bucket_cursor = (int*)(ws + o); o = align(o + 256 * 4);
    int* cnt       = (int*)(ws + o); o = align(o + (size_t)N_NODES * 4);
    int* row_start = (int*)(ws + o); o = align(o + (size_t)N_NODES * 4);
    unsigned* binned = (unsigned*)(ws + o); o = align(o + ((size_t)NB << CAPLOG) * 4);
    int* csr_src   = (int*)(ws + o); o = align(o + ((size_t)NB << CAPLOG) * 4);
    unsigned short* xb  = (unsigned short*)(ws + o); o = align(o + (size_t)N_NODES * 64 * 2);
    unsigned short* h1b = (unsigned short*)(ws + o); o = align(o + (size_t)N_NODES * 64 * 2);
    float* Wt1 = (float*)(ws + o); o = align(o + 64 * 128 * 4);
    float* Wt2 = (float*)(ws + o); o = align(o + 32 * 128 * 4);

    init_pad_kernel<<<1 + PAD_BLOCKS, 256, 0, stream>>>(x, W1, W2, xb,
                                                        bucket_cursor, Wt1, Wt2);
    bucket_bin<<<NBLK_A, 256, 0, stream>>>(src, dst, bucket_cursor, binned);
    bucket_fine<<<NB, 256, 0, stream>>>(binned, bucket_cursor,
                                        cnt, row_start, csr_src);

    layer1_fused<<<N_NODES / 16, 256, 0, stream>>>(xb, csr_src, row_start, cnt,
                                                   Wt1, b1, h1b);
    layer23_fused<<<N_NODES / 16, 256, 0, stream>>>(h1b, csr_src, row_start, cnt,
                                                    Wt2, b2, W3, b3, out);
}

// Round 12
// 292.178 us; speedup vs baseline: 1.3135x; 1.3135x over previous
//
#include <hip/hip_runtime.h>
#include <hip/hip_bf16.h>

#define N_NODES 100000
#define N_EDGES 1600000
#define IN_CH 50
#define NPB 512                                   // nodes per bucket (dst >> 9)
#define NB ((N_NODES + NPB - 1) / NPB)            // 196 buckets
#define CAPLOG 14                                 // 16384 slots per bucket (max ~8.6K)
#define EPB 4096
#define NBLK_A ((N_EDGES + EPB - 1) / EPB)        // 391 blocks
#define PAD_BLOCKS ((N_NODES * 64) / 256)         // 25000

// ---- 1. init: block 0 = cursors + W transposes (lane-coalesced float4 layout);
//         blocks 1.. = pad x->xb bf16 ----
// Wq1 float4 layout: Wq1[k4*64 + j] = {Wt1row_j[4k4+0..3]} where
//   Wt1row_j[k] = k<50 ? W1[k][j] : (64<=k<114 ? W1[k-14][j] : 0)
// Wq2 float4 layout: Wq2[k4*32 + j] = {W2[4k4+0..3][j]}
__global__ __launch_bounds__(256) void init_pad_kernel(
    const float* __restrict__ x, const float* __restrict__ W1,
    const float* __restrict__ W2, unsigned short* __restrict__ xb,
    int* __restrict__ bucket_cursor, float* __restrict__ Wq1,
    float* __restrict__ Wq2) {
    if (blockIdx.x == 0) {
        int t = threadIdx.x;
        if (t < NB) bucket_cursor[t] = t << CAPLOG;
        for (int idx = t; idx < 64 * 128; idx += 256) {   // 8192 floats
            int e  = idx & 3;
            int j  = (idx >> 2) & 63;
            int k4 = idx >> 8;
            int k  = k4 * 4 + e;
            float v = 0.0f;
            if (k < IN_CH) v = W1[k * 64 + j];
            else if (k >= 64 && k < 64 + IN_CH) v = W1[(k - 14) * 64 + j];
            Wq1[idx] = v;
        }
        for (int idx = t; idx < 32 * 128; idx += 256) {   // 4096 floats
            int e  = idx & 3;
            int j  = (idx >> 2) & 31;
            int k4 = idx >> 7;
            int k  = k4 * 4 + e;
            Wq2[idx] = W2[k * 32 + j];
        }
    } else {
        int t = (blockIdx.x - 1) * 256 + threadIdx.x;     // < N_NODES*64
        int n = t >> 6, c = t & 63;
        float v = (c < IN_CH) ? x[n * IN_CH + c] : 0.0f;
        __hip_bfloat16 hb = __float2bfloat16(v);
        xb[t] = *(unsigned short*)&hb;
    }
}

// ---- 2. bin edges as packed u32 into fixed-capacity buckets ----
__global__ __launch_bounds__(256) void bucket_bin(const int* __restrict__ src,
                                                  const int* __restrict__ dst,
                                                  int* __restrict__ bucket_cursor,
                                                  unsigned* __restrict__ binned) {
    __shared__ int bc[NB];
    __shared__ int boff[NB];
    int t = threadIdx.x;
    if (t < NB) bc[t] = 0;
    __syncthreads();
    int e0 = blockIdx.x * EPB;
    int e1 = min(e0 + EPB, N_EDGES);
    for (int i = e0 + t; i < e1; i += 256)
        atomicAdd(&bc[dst[i] >> 9], 1);
    __syncthreads();
    if (t < NB) {
        int v = bc[t];
        boff[t] = v ? atomicAdd(&bucket_cursor[t], v) : 0;
        bc[t] = 0;                                 // reuse as local cursor
    }
    __syncthreads();
    for (int i = e0 + t; i < e1; i += 256) {
        int d = dst[i];
        int b = d >> 9;
        int k = atomicAdd(&bc[b], 1);
        binned[boff[b] + k] = ((unsigned)(d & 511) << 17) | (unsigned)src[i];
    }
}

// ---- 3. per-bucket fine sort (u32 payload) -> cnt, row_start, csr_src ----
__global__ __launch_bounds__(256) void bucket_fine(
    const unsigned* __restrict__ binned, const int* __restrict__ bucket_cursor,
    int* __restrict__ cnt, int* __restrict__ row_start, int* __restrict__ csr_src) {
    __shared__ int lcnt[NPB];
    __shared__ int lofs[NPB];
    __shared__ int sc[256];
    int t = threadIdx.x;
    int b = blockIdx.x;
    int nbase = b * NPB;
    int bbase = b << CAPLOG;
    int ecnt  = bucket_cursor[b] - bbase;
    lcnt[t] = 0; lcnt[t + 256] = 0;
    __syncthreads();
    for (int i = t; i < ecnt; i += 256)
        atomicAdd(&lcnt[(binned[bbase + i] >> 17) & 511], 1);
    __syncthreads();
    int v0 = lcnt[2 * t], v1 = lcnt[2 * t + 1];
    int pair = v0 + v1;
    sc[t] = pair;
    __syncthreads();
    for (int off = 1; off < 256; off <<= 1) {
        int tmp = (t >= off) ? sc[t - off] : 0;
        __syncthreads();
        sc[t] += tmp;
        __syncthreads();
    }
    int excl = sc[t] - pair;
    lofs[2 * t] = excl;
    lofs[2 * t + 1] = excl + v0;
    __syncthreads();
    {
        int n0 = nbase + t;
        if (n0 < N_NODES) { cnt[n0] = lcnt[t]; row_start[n0] = bbase + lofs[t]; }
        int n1 = nbase + t + 256;
        if (n1 < N_NODES) { cnt[n1] = lcnt[t + 256]; row_start[n1] = bbase + lofs[t + 256]; }
    }
    __syncthreads();
    for (int i = t; i < ecnt; i += 256) {
        unsigned p = binned[bbase + i];
        int d = (int)((p >> 17) & 511);
        int k = atomicAdd(&lofs[d], 1);
        csr_src[bbase + k] = (int)(p & 0x1FFFFu);
    }
}

// unpack 8 bf16 from uint4, predicated fma into acc[0..8)
__device__ __forceinline__ void upadd8(float* a, uint4 v, float p) {
    a[0] = fmaf(p, __uint_as_float(v.x << 16), a[0]);
    a[1] = fmaf(p, __uint_as_float(v.x & 0xffff0000u), a[1]);
    a[2] = fmaf(p, __uint_as_float(v.y << 16), a[2]);
    a[3] = fmaf(p, __uint_as_float(v.y & 0xffff0000u), a[3]);
    a[4] = fmaf(p, __uint_as_float(v.z << 16), a[4]);
    a[5] = fmaf(p, __uint_as_float(v.z & 0xffff0000u), a[5]);
    a[6] = fmaf(p, __uint_as_float(v.w << 16), a[6]);
    a[7] = fmaf(p, __uint_as_float(v.w & 0xffff0000u), a[7]);
}

// wave-local LDS fence
#define WAVE_LDS_FENCE() __asm__ volatile("s_waitcnt lgkmcnt(0)" ::: "memory")

// Gather-mean of 4 nodes per wave, chains interleaved (proven R7/R10 shape).
__device__ __forceinline__ void gather4(
    const unsigned short* __restrict__ featb, const int* __restrict__ csr_src,
    const int* __restrict__ row_start, const int* __restrict__ cnt,
    int nb, int lane, float acc[4][8]) {
    int g  = lane >> 3;
    int cw = (lane & 7) * 8;
    int start[4], deg[4], sv[4];
    int dmax = 0;
    #pragma unroll
    for (int i = 0; i < 4; ++i) {
        start[i] = row_start[nb + i];
        deg[i]   = cnt[nb + i];
        dmax = max(dmax, deg[i]);
        #pragma unroll
        for (int c = 0; c < 8; ++c) acc[i][c] = 0.f;
    }
    #pragma unroll
    for (int i = 0; i < 4; ++i)
        sv[i] = (lane < deg[i]) ? csr_src[start[i] + lane] : 0;

    #pragma unroll
    for (int cb = 0; cb < 64; cb += 16) {
        if (cb >= dmax) break;                 // wave-uniform
        #pragma unroll
        for (int i = 0; i < 4; ++i) {
            int rem = deg[i] - cb;
            if (rem > 0) {                     // wave-uniform
                int s0 = __shfl(sv[i], cb + g);
                int s1 = __shfl(sv[i], cb + 8 + g);
                float p0 = (g < rem) ? 1.f : 0.f;
                float p1 = (g + 8 < rem) ? 1.f : 0.f;
                uint4 v0 = *(const uint4*)(featb + s0 * 64 + cw);
                uint4 v1 = *(const uint4*)(featb + s1 * 64 + cw);
                upadd8(acc[i], v0, p0);
                upadd8(acc[i], v1, p1);
            }
        }
    }
    if (dmax > 64) {                           // rare tail
        for (int i = 0; i < 4; ++i) {
            for (int c0 = 64; c0 < deg[i]; c0 += 64) {
                int rem = deg[i] - c0; if (rem > 64) rem = 64;
                int sx = (lane < rem) ? csr_src[start[i] + c0 + lane] : 0;
                for (int cb = 0; cb < rem; cb += 16) {
                    int s0 = __shfl(sx, cb + g);
                    int s1 = __shfl(sx, cb + 8 + g);
                    float p0 = (cb + g < rem) ? 1.f : 0.f;
                    float p1 = (cb + 8 + g < rem) ? 1.f : 0.f;
                    uint4 v0 = *(const uint4*)(featb + s0 * 64 + cw);
                    uint4 v1 = *(const uint4*)(featb + s1 * 64 + cw);
                    upadd8(acc[i], v0, p0);
                    upadd8(acc[i], v1, p1);
                }
            }
        }
    }
    #pragma unroll
    for (int i = 0; i < 4; ++i) {
        float inv = 1.0f / fmaxf((float)deg[i], 1.0f);
        #pragma unroll
        for (int c = 0; c < 8; ++c) {
            float t = acc[i][c];
            t += __shfl_xor(t, 8);
            t += __shfl_xor(t, 16);
            t += __shfl_xor(t, 32);
            acc[i][c] = t * inv;
        }
    }
}

__device__ __forceinline__ float bf16u(unsigned short u) {
    return __uint_as_float(((unsigned)u) << 16);
}

// ---- 4. layer 1: 4 nodes/wave; gather(xb) + GEMM via Wq1 (lane-coalesced) -> h1b ----
__global__ __launch_bounds__(256) void layer1_fused(
    const unsigned short* __restrict__ xb,
    const int* __restrict__ csr_src, const int* __restrict__ row_start,
    const int* __restrict__ cnt, const float* __restrict__ Wq1,
    const float* __restrict__ b1, unsigned short* __restrict__ h1b) {
    int wv   = threadIdx.x >> 6;
    int lane = threadIdx.x & 63;
    int nb   = (blockIdx.x * 4 + wv) * 4;      // N_NODES % 16 == 0

    float acc[4][8];
    gather4(xb, csr_src, row_start, cnt, nb, lane, acc);

    // feat rows of 128: [0,64)=self (xb incl. zero pad), [64,128)=mean
    __shared__ __align__(16) float feat[4][4][128];
    #pragma unroll
    for (int i = 0; i < 4; ++i) {
        feat[wv][i][lane] = bf16u(xb[((nb + i) << 6) + lane]);
        if (lane < 8) {
            *(float4*)&feat[wv][i][64 + lane * 8] =
                make_float4(acc[i][0], acc[i][1], acc[i][2], acc[i][3]);
            *(float4*)&feat[wv][i][64 + lane * 8 + 4] =
                make_float4(acc[i][4], acc[i][5], acc[i][6], acc[i][7]);
        }
    }
    WAVE_LDS_FENCE();

    float ao[4];
    float bb = b1[lane];
    #pragma unroll
    for (int i = 0; i < 4; ++i) ao[i] = bb;
    const float4* wq = (const float4*)Wq1;
    #pragma unroll 4
    for (int k4 = 0; k4 < 32; ++k4) {
        float4 w = wq[k4 * 64 + lane];         // consecutive lanes -> consecutive 16B
        #pragma unroll
        for (int i = 0; i < 4; ++i) {
            float4 f = *(const float4*)&feat[wv][i][k4 * 4];
            ao[i] = fmaf(f.x, w.x, ao[i]);
            ao[i] = fmaf(f.y, w.y, ao[i]);
            ao[i] = fmaf(f.z, w.z, ao[i]);
            ao[i] = fmaf(f.w, w.w, ao[i]);
        }
    }
    #pragma unroll
    for (int i = 0; i < 4; ++i) {
        float r = fmaxf(ao[i], 0.f);
        __hip_bfloat16 hb = __float2bfloat16(r);
        h1b[((nb + i) << 6) + lane] = *(unsigned short*)&hb;
    }
}

// ---- 5. layers 2+3: 4 nodes/wave; gather(h1b) + GEMM via Wq2 + ReLU + dot(W3) ----
__global__ __launch_bounds__(256) void layer23_fused(
    const unsigned short* __restrict__ h1b,
    const int* __restrict__ csr_src, const int* __restrict__ row_start,
    const int* __restrict__ cnt, const float* __restrict__ Wq2,
    const float* __restrict__ b2, const float* __restrict__ W3,
    const float* __restrict__ b3, float* __restrict__ out) {
    int wv   = threadIdx.x >> 6;
    int lane = threadIdx.x & 63;
    int nb   = (blockIdx.x * 4 + wv) * 4;

    float acc[4][8];
    gather4(h1b, csr_src, row_start, cnt, nb, lane, acc);

    __shared__ __align__(16) float featL[4][4][128];   // [0,64)=self, [64,128)=mean
    #pragma unroll
    for (int i = 0; i < 4; ++i) {
        featL[wv][i][lane] = bf16u(h1b[((nb + i) << 6) + lane]);
        if (lane < 8) {
            *(float4*)&featL[wv][i][64 + lane * 8] =
                make_float4(acc[i][0], acc[i][1], acc[i][2], acc[i][3]);
            *(float4*)&featL[wv][i][64 + lane * 8 + 4] =
                make_float4(acc[i][4], acc[i][5], acc[i][6], acc[i][7]);
        }
    }
    WAVE_LDS_FENCE();

    int hh = lane >> 5;                        // half-wave id: nodes nb+hh, nb+2+hh
    int j  = lane & 31;
    float a0 = b2[j], a1 = a0;
    const float4* wq = (const float4*)Wq2;
    #pragma unroll 4
    for (int k4 = 0; k4 < 32; ++k4) {
        float4 w  = wq[k4 * 32 + j];           // lanes 0-31 / 32-63 coalesced
        float4 f0 = *(const float4*)&featL[wv][hh][k4 * 4];
        float4 f1 = *(const float4*)&featL[wv][2 + hh][k4 * 4];
        a0 = fmaf(f0.x, w.x, a0); a0 = fmaf(f0.y, w.y, a0);
        a0 = fmaf(f0.z, w.z, a0); a0 = fmaf(f0.w, w.w, a0);
        a1 = fmaf(f1.x, w.x, a1); a1 = fmaf(f1.y, w.y, a1);
        a1 = fmaf(f1.z, w.z, a1); a1 = fmaf(f1.w, w.w, a1);
    }
    float w3 = W3[j];
    float c3 = b3[0];
    float v0 = fmaxf(a0, 0.f) * w3;
    float v1 = fmaxf(a1, 0.f) * w3;
    #pragma unroll
    for (int off = 1; off <= 16; off <<= 1) {
        v0 += __shfl_xor(v0, off);
        v1 += __shfl_xor(v1, off);
    }
    if (j == 0) {
        out[nb + hh]     = v0 + c3;
        out[nb + 2 + hh] = v1 + c3;
    }
}

extern "C" void kernel_launch(void* const* d_in, const int* in_sizes, int n_in,
                              void* d_out, int out_size, void* d_ws, size_t ws_size,
                              hipStream_t stream) {
    const float* x   = (const float*)d_in[0];
    const int*   ei  = (const int*)d_in[1];
    const int*   src = ei;
    const int*   dst = ei + N_EDGES;
    const float* W1  = (const float*)d_in[2];
    const float* b1  = (const float*)d_in[3];
    const float* W2  = (const float*)d_in[4];
    const float* b2  = (const float*)d_in[5];
    const float* W3  = (const float*)d_in[6];
    const float* b3  = (const float*)d_in[7];
    float* out = (float*)d_out;

    // ws (~52 MB): cursor | cnt | row_start | binned u32[NB<<14] 12.85MB |
    //   csr_src[NB<<14] 12.85MB | xb bf16 12.8MB | h1b bf16 12.8MB | Wq1 32KB | Wq2 16KB
    char* ws = (char*)d_ws;
    auto align = [](size_t v) { return (v + 255) & ~(size_t)255; };
    size_t o = 0;
    int* bucket_cursor = (int*)(ws + o); o = align(o + 256 * 4);
    int* cnt       = (int*)(ws + o); o = align(o + (size_t)N_NODES * 4);
    int* row_start = (int*)(ws + o); o = align(o + (size_t)N_NODES * 4);
    unsigned* binned = (unsigned*)(ws + o); o = align(o + ((size_t)NB << CAPLOG) * 4);
    int* csr_src   = (int*)(ws + o); o = align(o + ((size_t)NB << CAPLOG) * 4);
    unsigned short* xb  = (unsigned short*)(ws + o); o = align(o + (size_t)N_NODES * 64 * 2);
    unsigned short* h1b = (unsigned short*)(ws + o); o = align(o + (size_t)N_NODES * 64 * 2);
    float* Wq1 = (float*)(ws + o); o = align(o + 64 * 128 * 4);
    float* Wq2 = (float*)(ws + o); o = align(o + 32 * 128 * 4);

    init_pad_kernel<<<1 + PAD_BLOCKS, 256, 0, stream>>>(x, W1, W2, xb,
                                                        bucket_cursor, Wq1, Wq2);
    bucket_bin<<<NBLK_A, 256, 0, stream>>>(src, dst, bucket_cursor, binned);
    bucket_fine<<<NB, 256, 0, stream>>>(binned, bucket_cursor,
                                        cnt, row_start, csr_src);

    layer1_fused<<<N_NODES / 16, 256, 0, stream>>>(xb, csr_src, row_start, cnt,
                                                   Wq1, b1, h1b);
    layer23_fused<<<N_NODES / 16, 256, 0, stream>>>(h1b, csr_src, row_start, cnt,
                                                    Wq2, b2, W3, b3, out);
}

// Round 13
// 268.344 us; speedup vs baseline: 1.4301x; 1.0888x over previous
//
#include <hip/hip_runtime.h>
#include <hip/hip_bf16.h>

#define N_NODES 100000
#define N_EDGES 1600000
#define IN_CH 50
#define NPB 512                                   // nodes per bucket (dst >> 9)
#define NB ((N_NODES + NPB - 1) / NPB)            // 196 buckets
#define CAPLOG 14                                 // 16384 slots/bucket (max ~8.6K used)
#define EPB 4096
#define NBLK_A ((N_EDGES + EPB - 1) / EPB)        // 391 blocks
#define PAD_BLOCKS ((N_NODES * 64) / 256)         // 25000

// ---- 1. bin edges into fixed-capacity buckets (+ extra blocks: pad x->xb bf16) ----
// cursor_rel[b] is RELATIVE (starts 0 via memset); slot = (b<<CAPLOG) + rel.
__global__ __launch_bounds__(256) void bin_pad_kernel(
    const int* __restrict__ src, const int* __restrict__ dst,
    int* __restrict__ cursor_rel, unsigned* __restrict__ binned,
    const float* __restrict__ x, unsigned short* __restrict__ xb) {
    if (blockIdx.x >= NBLK_A) {                    // pad lane
        int t = (blockIdx.x - NBLK_A) * 256 + threadIdx.x;   // < N_NODES*64
        int n = t >> 6, c = t & 63;
        float v = (c < IN_CH) ? x[n * IN_CH + c] : 0.0f;
        __hip_bfloat16 hb = __float2bfloat16(v);
        xb[t] = *(unsigned short*)&hb;
        return;
    }
    __shared__ int bc[NB];
    __shared__ int boff[NB];                       // absolute base for this block
    int t = threadIdx.x;
    if (t < NB) bc[t] = 0;
    __syncthreads();
    int e0 = blockIdx.x * EPB;
    int e1 = min(e0 + EPB, N_EDGES);
    for (int i = e0 + t; i < e1; i += 256)
        atomicAdd(&bc[dst[i] >> 9], 1);
    __syncthreads();
    if (t < NB) {
        int v = bc[t];
        int rel = v ? atomicAdd(&cursor_rel[t], v) : 0;
        boff[t] = (t << CAPLOG) + rel;
        bc[t] = 0;                                 // reuse as local cursor
    }
    __syncthreads();
    for (int i = e0 + t; i < e1; i += 256) {
        int d = dst[i];
        int b = d >> 9;
        int k = atomicAdd(&bc[b], 1);
        binned[boff[b] + k] = ((unsigned)(d & 511) << 17) | (unsigned)src[i];
    }
}

// ---- 2. per-bucket fine sort (u32 payload) -> cnt, row_start, csr_src ----
__global__ __launch_bounds__(256) void bucket_fine(
    const unsigned* __restrict__ binned, const int* __restrict__ cursor_rel,
    int* __restrict__ cnt, int* __restrict__ row_start, int* __restrict__ csr_src) {
    __shared__ int lcnt[NPB];
    __shared__ int lofs[NPB];
    __shared__ int sc[256];
    int t = threadIdx.x;
    int b = blockIdx.x;
    int nbase = b * NPB;
    int bbase = b << CAPLOG;
    int ecnt  = cursor_rel[b];
    lcnt[t] = 0; lcnt[t + 256] = 0;
    __syncthreads();
    for (int i = t; i < ecnt; i += 256)
        atomicAdd(&lcnt[(binned[bbase + i] >> 17) & 511], 1);
    __syncthreads();
    int v0 = lcnt[2 * t], v1 = lcnt[2 * t + 1];
    int pair = v0 + v1;
    sc[t] = pair;
    __syncthreads();
    for (int off = 1; off < 256; off <<= 1) {
        int tmp = (t >= off) ? sc[t - off] : 0;
        __syncthreads();
        sc[t] += tmp;
        __syncthreads();
    }
    int excl = sc[t] - pair;
    lofs[2 * t] = excl;
    lofs[2 * t + 1] = excl + v0;
    __syncthreads();
    {
        int n0 = nbase + t;
        if (n0 < N_NODES) { cnt[n0] = lcnt[t]; row_start[n0] = bbase + lofs[t]; }
        int n1 = nbase + t + 256;
        if (n1 < N_NODES) { cnt[n1] = lcnt[t + 256]; row_start[n1] = bbase + lofs[t + 256]; }
    }
    __syncthreads();
    for (int i = t; i < ecnt; i += 256) {
        unsigned p = binned[bbase + i];
        int d = (int)((p >> 17) & 511);
        int k = atomicAdd(&lofs[d], 1);
        csr_src[bbase + k] = (int)(p & 0x1FFFFu);
    }
}

// unpack 8 bf16 from uint4, predicated fma into acc[0..8)
__device__ __forceinline__ void upadd8(float* a, uint4 v, float p) {
    a[0] = fmaf(p, __uint_as_float(v.x << 16), a[0]);
    a[1] = fmaf(p, __uint_as_float(v.x & 0xffff0000u), a[1]);
    a[2] = fmaf(p, __uint_as_float(v.y << 16), a[2]);
    a[3] = fmaf(p, __uint_as_float(v.y & 0xffff0000u), a[3]);
    a[4] = fmaf(p, __uint_as_float(v.z << 16), a[4]);
    a[5] = fmaf(p, __uint_as_float(v.z & 0xffff0000u), a[5]);
    a[6] = fmaf(p, __uint_as_float(v.w << 16), a[6]);
    a[7] = fmaf(p, __uint_as_float(v.w & 0xffff0000u), a[7]);
}

// wave-local LDS fence: LDS ops of one wave complete in order; no block barrier.
#define WAVE_LDS_FENCE() __asm__ volatile("s_waitcnt lgkmcnt(0)" ::: "memory")

// Gather-mean of 4 nodes per wave, chains interleaved (proven R7/R10 shape).
__device__ __forceinline__ void gather4(
    const unsigned short* __restrict__ featb, const int* __restrict__ csr_src,
    const int* __restrict__ row_start, const int* __restrict__ cnt,
    int nb, int lane, float acc[4][8]) {
    int g  = lane >> 3;
    int cw = (lane & 7) * 8;
    int start[4], deg[4], sv[4];
    int dmax = 0;
    #pragma unroll
    for (int i = 0; i < 4; ++i) {
        start[i] = row_start[nb + i];
        deg[i]   = cnt[nb + i];
        dmax = max(dmax, deg[i]);
        #pragma unroll
        for (int c = 0; c < 8; ++c) acc[i][c] = 0.f;
    }
    #pragma unroll
    for (int i = 0; i < 4; ++i)
        sv[i] = (lane < deg[i]) ? csr_src[start[i] + lane] : 0;

    #pragma unroll
    for (int cb = 0; cb < 64; cb += 16) {
        if (cb >= dmax) break;                 // wave-uniform
        #pragma unroll
        for (int i = 0; i < 4; ++i) {
            int rem = deg[i] - cb;
            if (rem > 0) {                     // wave-uniform
                int s0 = __shfl(sv[i], cb + g);
                int s1 = __shfl(sv[i], cb + 8 + g);
                float p0 = (g < rem) ? 1.f : 0.f;
                float p1 = (g + 8 < rem) ? 1.f : 0.f;
                uint4 v0 = *(const uint4*)(featb + s0 * 64 + cw);
                uint4 v1 = *(const uint4*)(featb + s1 * 64 + cw);
                upadd8(acc[i], v0, p0);
                upadd8(acc[i], v1, p1);
            }
        }
    }
    if (dmax > 64) {                           // rare tail
        for (int i = 0; i < 4; ++i) {
            for (int c0 = 64; c0 < deg[i]; c0 += 64) {
                int rem = deg[i] - c0; if (rem > 64) rem = 64;
                int sx = (lane < rem) ? csr_src[start[i] + c0 + lane] : 0;
                for (int cb = 0; cb < rem; cb += 16) {
                    int s0 = __shfl(sx, cb + g);
                    int s1 = __shfl(sx, cb + 8 + g);
                    float p0 = (cb + g < rem) ? 1.f : 0.f;
                    float p1 = (cb + 8 + g < rem) ? 1.f : 0.f;
                    uint4 v0 = *(const uint4*)(featb + s0 * 64 + cw);
                    uint4 v1 = *(const uint4*)(featb + s1 * 64 + cw);
                    upadd8(acc[i], v0, p0);
                    upadd8(acc[i], v1, p1);
                }
            }
        }
    }
    #pragma unroll
    for (int i = 0; i < 4; ++i) {
        float inv = 1.0f / fmaxf((float)deg[i], 1.0f);
        #pragma unroll
        for (int c = 0; c < 8; ++c) {
            float t = acc[i][c];
            t += __shfl_xor(t, 8);
            t += __shfl_xor(t, 16);
            t += __shfl_xor(t, 32);
            acc[i][c] = t * inv;
        }
    }
}

__device__ __forceinline__ float bf16u(unsigned short u) {
    return __uint_as_float(((unsigned)u) << 16);
}

// ---- 3. layer 1 (R10-proven): 4 nodes/wave; gather(xb) + scalar-broadcast GEMM ----
__global__ __launch_bounds__(256) void layer1_fused(
    const unsigned short* __restrict__ xb,
    const int* __restrict__ csr_src, const int* __restrict__ row_start,
    const int* __restrict__ cnt, const float* __restrict__ W1,
    const float* __restrict__ b1, unsigned short* __restrict__ h1b) {
    int wv   = threadIdx.x >> 6;
    int lane = threadIdx.x & 63;
    int nb   = (blockIdx.x * 4 + wv) * 4;      // N_NODES % 16 == 0

    float acc[4][8];
    gather4(xb, csr_src, row_start, cnt, nb, lane, acc);

    __shared__ __align__(16) float selfF[4][4][64];
    __shared__ __align__(16) float meanF[4][4][64];
    #pragma unroll
    for (int i = 0; i < 4; ++i) {
        selfF[wv][i][lane] = bf16u(xb[((nb + i) << 6) + lane]);
        if (lane < 8) {
            *(float4*)&meanF[wv][i][lane * 8] =
                make_float4(acc[i][0], acc[i][1], acc[i][2], acc[i][3]);
            *(float4*)&meanF[wv][i][lane * 8 + 4] =
                make_float4(acc[i][4], acc[i][5], acc[i][6], acc[i][7]);
        }
    }
    WAVE_LDS_FENCE();

    float ao[4];
    float bb = b1[lane];
    #pragma unroll
    for (int i = 0; i < 4; ++i) ao[i] = bb;
    #pragma unroll
    for (int k = 0; k < IN_CH; ++k) {
        float w = W1[k * 64 + lane];           // lanes coalesced, reused x4
        #pragma unroll
        for (int i = 0; i < 4; ++i) ao[i] = fmaf(selfF[wv][i][k], w, ao[i]);
    }
    #pragma unroll
    for (int k = 0; k < IN_CH; ++k) {
        float w = W1[(IN_CH + k) * 64 + lane];
        #pragma unroll
        for (int i = 0; i < 4; ++i) ao[i] = fmaf(meanF[wv][i][k], w, ao[i]);
    }
    #pragma unroll
    for (int i = 0; i < 4; ++i) {
        float r = fmaxf(ao[i], 0.f);
        __hip_bfloat16 hb = __float2bfloat16(r);
        h1b[((nb + i) << 6) + lane] = *(unsigned short*)&hb;
    }
}

// ---- 4. layers 2+3 (R10-proven): gather(h1b) + scalar-broadcast GEMM + dot(W3) ----
__global__ __launch_bounds__(256) void layer23_fused(
    const unsigned short* __restrict__ h1b,
    const int* __restrict__ csr_src, const int* __restrict__ row_start,
    const int* __restrict__ cnt, const float* __restrict__ W2,
    const float* __restrict__ b2, const float* __restrict__ W3,
    const float* __restrict__ b3, float* __restrict__ out) {
    int wv   = threadIdx.x >> 6;
    int lane = threadIdx.x & 63;
    int nb   = (blockIdx.x * 4 + wv) * 4;

    float acc[4][8];
    gather4(h1b, csr_src, row_start, cnt, nb, lane, acc);

    __shared__ __align__(16) float featL[4][4][128];   // [0,64)=self, [64,128)=mean
    #pragma unroll
    for (int i = 0; i < 4; ++i) {
        featL[wv][i][lane] = bf16u(h1b[((nb + i) << 6) + lane]);
        if (lane < 8) {
            *(float4*)&featL[wv][i][64 + lane * 8] =
                make_float4(acc[i][0], acc[i][1], acc[i][2], acc[i][3]);
            *(float4*)&featL[wv][i][64 + lane * 8 + 4] =
                make_float4(acc[i][4], acc[i][5], acc[i][6], acc[i][7]);
        }
    }
    WAVE_LDS_FENCE();

    int hh = lane >> 5;                        // half-wave id: nodes nb+hh, nb+2+hh
    int j  = lane & 31;
    float a0 = b2[j], a1 = a0;
    #pragma unroll
    for (int k = 0; k < 128; ++k) {
        float w = W2[k * 32 + j];              // lanes coalesced, reused x2
        a0 = fmaf(featL[wv][hh][k],     w, a0);
        a1 = fmaf(featL[wv][2 + hh][k], w, a1);
    }
    float w3 = W3[j];
    float c3 = b3[0];
    float v0 = fmaxf(a0, 0.f) * w3;
    float v1 = fmaxf(a1, 0.f) * w3;
    #pragma unroll
    for (int off = 1; off <= 16; off <<= 1) {
        v0 += __shfl_xor(v0, off);
        v1 += __shfl_xor(v1, off);
    }
    if (j == 0) {
        out[nb + hh]     = v0 + c3;
        out[nb + 2 + hh] = v1 + c3;
    }
}

extern "C" void kernel_launch(void* const* d_in, const int* in_sizes, int n_in,
                              void* d_out, int out_size, void* d_ws, size_t ws_size,
                              hipStream_t stream) {
    const float* x   = (const float*)d_in[0];
    const int*   ei  = (const int*)d_in[1];
    const int*   src = ei;
    const int*   dst = ei + N_EDGES;
    const float* W1  = (const float*)d_in[2];
    const float* b1  = (const float*)d_in[3];
    const float* W2  = (const float*)d_in[4];
    const float* b2  = (const float*)d_in[5];
    const float* W3  = (const float*)d_in[6];
    const float* b3  = (const float*)d_in[7];
    float* out = (float*)d_out;

    // ws (~52 MB): cursor_rel | cnt | row_start | binned u32[NB<<14] 12.85MB |
    //   csr_src[NB<<14] 12.85MB | xb bf16 12.8MB | h1b bf16 12.8MB
    char* ws = (char*)d_ws;
    auto align = [](size_t v) { return (v + 255) & ~(size_t)255; };
    size_t o = 0;
    int* cursor_rel = (int*)(ws + o); o = align(o + 256 * 4);
    int* cnt       = (int*)(ws + o); o = align(o + (size_t)N_NODES * 4);
    int* row_start = (int*)(ws + o); o = align(o + (size_t)N_NODES * 4);
    unsigned* binned = (unsigned*)(ws + o); o = align(o + ((size_t)NB << CAPLOG) * 4);
    int* csr_src   = (int*)(ws + o); o = align(o + ((size_t)NB << CAPLOG) * 4);
    unsigned short* xb  = (unsigned short*)(ws + o); o = align(o + (size_t)N_NODES * 64 * 2);
    unsigned short* h1b = (unsigned short*)(ws + o); o = align(o + (size_t)N_NODES * 64 * 2);

    hipMemsetAsync(cursor_rel, 0, 256 * sizeof(int), stream);

    bin_pad_kernel<<<NBLK_A + PAD_BLOCKS, 256, 0, stream>>>(src, dst, cursor_rel,
                                                            binned, x, xb);
    bucket_fine<<<NB, 256, 0, stream>>>(binned, cursor_rel, cnt, row_start, csr_src);

    layer1_fused<<<N_NODES / 16, 256, 0, stream>>>(xb, csr_src, row_start, cnt,
                                                   W1, b1, h1b);
    layer23_fused<<<N_NODES / 16, 256, 0, stream>>>(h1b, csr_src, row_start, cnt,
                                                    W2, b2, W3, b3, out);
}